// Round 12
// baseline (228.844 us; speedup 1.0000x reference)
//
#include <hip/hip_runtime.h>
#include <stdint.h>
#include <stddef.h>

// RadialCTC: cosine logits (norm_scale=32) -> log_softmax -> CTC(sum).
// Strategy: never materialize the (16384 x 1296) logits. GEMM (f16 MFMA)
// computes per-row sum(exp(logit)) fused in the epilogue; label log-probs via
// small f16 MFMA gather-GEMM; CTC alpha recursion one wave per sample.
// R4: gather on MFMA. R5: shfl=ds_bpermute ~120cyc; fp8 non-scaled = f16 rate.
// R6: DPP wave_shr neighbor access. R7: log-pair-fusion regressed.
// R8: linear f32 FAILED (cross-lane spread > f32 window).
// R9: linear f64 + wave-uniform pow2 renorm: 30us = 144 cyc/step (f64 dep
//     latency dominates). R10: fusion + DPP-epilogue regressed, reverted.
// R11: LDS XOR swizzle NEUTRAL: conflicts cost only ~4cyc/read (33%), hidden
//     by wave overlap. gemm is structurally LDS+barrier bound: 45k cyc/CU
//     LDS pipe vs 2.8us MFMA; staged traffic is L2-resident anyway.
// R12: (a) gemm LDS-FREE: A/B fragments loaded global->VGPR direct (L2/L3
//     resident, 16B contiguous per lane), full K unroll, no barriers; grid
//     (bn,bm) so the 11 same-bm blocks share the A slab in L2.
//     (b) ctc per-lane (f32 mantissa, int exponent) state: term alignment by
//     bit-assembled 2^d scales; no f64, no transcendentals, NO renorm (per-
//     lane exponent is unbounded). Dead lanes hold e=-2^28.

typedef _Float16 f16;
typedef _Float16 f16x8 __attribute__((ext_vector_type(8)));
typedef float f32x4 __attribute__((ext_vector_type(4)));
typedef __attribute__((address_space(1))) void* as1_void_ptr;
typedef __attribute__((address_space(3))) void* as3_void_ptr;

#define TT 512
#define NN 32
#define CC 1296
#define DD 512
#define SS 30
#define CP 1408   // C padded to 11*128 for GEMM tiling (pad rows are zero)
#define LL 61     // 2*S+1 CTC states
#define NEGINF (-1e9f)
#define NORM_SCALE 32.0f
#define LOG2E 1.4426950408889634f
#define LN2   0.6931471805599453f
#define EMIN  (-(1 << 28))   // exponent of "zero" lanes

__device__ __forceinline__ float fexp2(float x) { return __builtin_amdgcn_exp2f(x); }
__device__ __forceinline__ float flog2(float x) { return __builtin_amdgcn_logf(x); }

// whole-wave shift-right-by-1 (DPP ctrl 0x138 = WAVE_SHR1); lane0 <- 0 bits
__device__ __forceinline__ float dpp_sr1_f32(float x) {
    return __int_as_float(__builtin_amdgcn_update_dpp(
        0, __float_as_int(x), 0x138, 0xF, 0xF, false));
}
__device__ __forceinline__ int dpp_sr1_i32(int x) {
    return __builtin_amdgcn_update_dpp(0, x, 0x138, 0xF, 0xF, false);
}

// ---- col sum-of-squares of W (D x C), partial over d-chunks, atomic ----
__global__ void colnorm_kernel(const float* __restrict__ W, float* __restrict__ ssq) {
    int c = blockIdx.x * 64 + threadIdx.x;
    if (c >= CC) return;
    int d0 = blockIdx.y * 64;
    float ss = 0.f;
    #pragma unroll 8
    for (int d = d0; d < d0 + 64; ++d) {
        float v = W[(size_t)d * CC + c];
        ss += v * v;
    }
    atomicAdd(&ssq[c], ss);
}

// ---- build padded transposed normalized weight w_t (CP x DD), f16 ----
__global__ void wt_kernel(const float* __restrict__ W, const float* __restrict__ ssq,
                          f16* __restrict__ wt) {
    int idx = blockIdx.x * 256 + threadIdx.x;   // idx < CP*DD
    int c = idx >> 9, d = idx & 511;
    float v = 0.f;
    if (c < CC) v = W[(size_t)d * CC + c] * rsqrtf(ssq[c]);
    wt[idx] = (f16)v;
}

// ---- feats row-normalize -> f16 (one wave per row) ----
__global__ __launch_bounds__(256) void fnorm_kernel(const float* __restrict__ feats,
                                                    f16* __restrict__ fn) {
    int wv = (blockIdx.x * 256 + threadIdx.x) >> 6;  // row id, 0..16383
    int lane = threadIdx.x & 63;
    const float4* src = (const float4*)(feats + (size_t)wv * DD) + lane * 2;
    float4 a = src[0], b = src[1];
    float ss = a.x*a.x + a.y*a.y + a.z*a.z + a.w*a.w
             + b.x*b.x + b.y*b.y + b.z*b.z + b.w*b.w;
    #pragma unroll
    for (int off = 32; off; off >>= 1) ss += __shfl_xor(ss, off);
    float r = rsqrtf(ss);
    f16x8 o;
    o[0]=(f16)(a.x*r); o[1]=(f16)(a.y*r); o[2]=(f16)(a.z*r); o[3]=(f16)(a.w*r);
    o[4]=(f16)(b.x*r); o[5]=(f16)(b.y*r); o[6]=(f16)(b.z*r); o[7]=(f16)(b.w*r);
    *(f16x8*)(fn + (size_t)wv * DD + lane * 8) = o;
}

// ---- LDS-free MFMA GEMM (A: 16384x512 f16, B^T: 1408x512 f16), fragments
//      loaded global->VGPR (L2/L3-resident), fused sum-exp epilogue. ----
__global__ __launch_bounds__(256) void gemm_sumexp_kernel(const f16* __restrict__ A,
                                                          const f16* __restrict__ B,
                                                          float* __restrict__ sumexp) {
    int bn = blockIdx.x, bm = blockIdx.y;  // grid(11,128): same-bm blocks adjacent
    int tid = threadIdx.x;
    int w = tid >> 6, lane = tid & 63;
    int wm = w >> 1, wn = w & 1;           // 2x2 wave grid -> 64x64 per wave
    int lm = lane & 15, hi = lane >> 4;
    // lane's A rows: bm*128 + wm*64 + i*16 + lm; k-offset hi*8 within kb*32
    const f16* arow = A + (size_t)(bm * 128 + wm * 64 + lm) * DD + hi * 8;
    const f16* brow = B + (size_t)(bn * 128 + wn * 64 + lm) * DD + hi * 8;
    f32x4 acc[4][4];
    f32x4 zero = {0.f, 0.f, 0.f, 0.f};
    #pragma unroll
    for (int i = 0; i < 4; ++i)
        #pragma unroll
        for (int j = 0; j < 4; ++j) acc[i][j] = zero;

    #pragma unroll
    for (int kb = 0; kb < 16; ++kb) {      // K=512, BK=32 (one MFMA K-step)
        f16x8 af[4], bf[4];
        #pragma unroll
        for (int i = 0; i < 4; ++i)
            af[i] = *(const f16x8*)(arow + (size_t)i * 16 * DD + kb * 32);
        #pragma unroll
        for (int j = 0; j < 4; ++j)
            bf[j] = *(const f16x8*)(brow + (size_t)j * 16 * DD + kb * 32);
        #pragma unroll
        for (int i = 0; i < 4; ++i)
            #pragma unroll
            for (int j = 0; j < 4; ++j)
                acc[i][j] = __builtin_amdgcn_mfma_f32_16x16x32_f16(af[i], bf[j], acc[i][j], 0, 0, 0);
    }
    // epilogue: per-row sum of exp(32*logit) over this block's 128 columns
    #pragma unroll
    for (int i = 0; i < 4; ++i) {
        float rs[4] = {0.f, 0.f, 0.f, 0.f};
        #pragma unroll
        for (int j = 0; j < 4; ++j) {
            int c = bn * 128 + wn * 64 + j * 16 + lm;   // C/D: col = lane&15
            bool ok = (c < CC);
            #pragma unroll
            for (int r = 0; r < 4; ++r)
                rs[r] += ok ? fexp2(acc[i][j][r] * (NORM_SCALE * LOG2E)) : 0.f;
        }
        #pragma unroll
        for (int off = 1; off < 16; off <<= 1) {        // sum over 16 cols
            #pragma unroll
            for (int r = 0; r < 4; ++r) rs[r] += __shfl_xor(rs[r], off);
        }
        if (lm == 0) {
            int rowb = bm * 128 + wm * 64 + i * 16 + hi * 4;  // row = quad*4+reg
            #pragma unroll
            for (int r = 0; r < 4; ++r) atomicAdd(&sumexp[rowb + r], rs[r]);
        }
    }
}

// ---- gather-GEMM (f16): per (n, 64-t chunk), P = Fn(64x512) x Wlab^T(32x512).
//      All 16 K-tiles staged up-front (A 64KB + B 32KB LDS), ONE barrier.
//      LDS channel-slot XOR swizzle (R11). ----
__global__ __launch_bounds__(256) void gather_kernel(const f16* __restrict__ fn,
                                                     const f16* __restrict__ wt,
                                                     const float* __restrict__ sumexp,
                                                     const int* __restrict__ labels,
                                                     float* __restrict__ lp_lab) {
    __shared__ __align__(16) f16 Bs[16 * 32 * 32];   // 32 KB: [kb][row][slot]
    __shared__ __align__(16) f16 As[16 * 64 * 32];   // 64 KB: [kb][row][slot]
    __shared__ float ls2[64];
    int n = blockIdx.x, t0 = blockIdx.y * 64;
    int tid = threadIdx.x;
    int w = tid >> 6, lane = tid & 63;
    int lm = lane & 15, hi = lane >> 4;
    int sw = (lm >> 1) & 3;

    #pragma unroll
    for (int it = 0; it < 8; ++it) {       // B: 2048 segs of 16B
        int s = it * 256 + tid;            // kb = s>>7, row = (s>>2)&31
        int row = (s >> 2) & 31;
        int ch = (s & 3) ^ ((row >> 1) & 3);
        int cls = (row == 0 || row > SS) ? 0 : labels[n * SS + row - 1];
        const f16* gb = wt + (size_t)cls * DD + (s >> 7) * 32 + ch * 8;
        __builtin_amdgcn_global_load_lds((as1_void_ptr)gb,
            (as3_void_ptr)&Bs[(it * 256 + w * 64) * 8], 16, 0, 0);
    }
    #pragma unroll
    for (int it = 0; it < 16; ++it) {      // A: 4096 segs of 16B
        int s = it * 256 + tid;            // kb = s>>8, row = (s>>2)&63
        int kb = s >> 8, row = (s >> 2) & 63;
        int ch = (s & 3) ^ ((row >> 1) & 3);
        const f16* ga = fn + (size_t)((t0 + row) * NN + n) * DD + kb * 32 + ch * 8;
        __builtin_amdgcn_global_load_lds((as1_void_ptr)ga,
            (as3_void_ptr)&As[(it * 256 + w * 64) * 8], 16, 0, 0);
    }
    if (tid < 64) ls2[tid] = flog2(sumexp[(size_t)(t0 + tid) * NN + n]);
    __syncthreads();

    f32x4 acc[2];
    acc[0] = (f32x4){0.f, 0.f, 0.f, 0.f};
    acc[1] = (f32x4){0.f, 0.f, 0.f, 0.f};
    #pragma unroll
    for (int kb = 0; kb < 16; ++kb) {
        f16x8 af  = *(const f16x8*)&As[kb * 2048 + (w * 16 + lm) * 32 + (hi ^ sw) * 8];
        f16x8 bf0 = *(const f16x8*)&Bs[kb * 1024 + lm * 32 + (hi ^ sw) * 8];
        f16x8 bf1 = *(const f16x8*)&Bs[kb * 1024 + (16 + lm) * 32 + (hi ^ sw) * 8];
        acc[0] = __builtin_amdgcn_mfma_f32_16x16x32_f16(af, bf0, acc[0], 0, 0, 0);
        acc[1] = __builtin_amdgcn_mfma_f32_16x16x32_f16(af, bf1, acc[1], 0, 0, 0);
    }
    #pragma unroll
    for (int jn = 0; jn < 2; ++jn) {
        int j = jn * 16 + lm;
        if (j >= 31) continue;
        float* dst = lp_lab + ((size_t)n * 31 + j) * TT + t0;
        #pragma unroll
        for (int r = 0; r < 4; ++r) {
            int tl = w * 16 + hi * 4 + r;
            dst[tl] = acc[jn][r] * (NORM_SCALE * LOG2E) - ls2[tl];
        }
    }
}

// ---- CTC alpha recursion, per-lane (f32 mantissa, int exponent) state.
//      beta = m * 2^e; terms aligned by bit-assembled 2^d scales; no f64,
//      no transcendentals in the chain, NO renorm. Dead lanes: e=EMIN. ----
__global__ void ctc_kernel(const float* __restrict__ lp_lab, const int* __restrict__ labels,
                           const int* __restrict__ in_lens, const int* __restrict__ lab_lens,
                           float* __restrict__ nll) {
    int n = blockIdx.x;
    int s = threadIdx.x;     // 64 lanes; states 0..60 valid
    bool valid = s < LL;
    int ext = (valid && (s & 1)) ? labels[n * SS + (s >> 1)] : 0;
    int jmap = (valid && (s & 1)) ? ((s >> 1) + 1) : 0;   // state -> class slot
    int ext2 = __shfl_up(ext, 2);
    bool skip = (s >= 2) && valid && (ext != ext2);
    int Tin = in_lens[n];    // wave-uniform; freeze == stop at t = Tin-1
    const float4* g0 = (const float4*)(lp_lab + ((size_t)n * 31 + jmap) * TT);

    float4 cur = g0[0];
    float4 nxt = g0[1];
    float4 nx2 = g0[2];
    float e0f = floorf(cur.x);
    float bm_ = (s <= 1) ? fexp2(cur.x - e0f) : 0.f;   // mantissa in [1,2)
    int   be  = (s <= 1) ? (int)e0f : EMIN;            // exponent

    auto stepM = [&](float lp) {
        // off-chain: P = mp * 2^ep
        float ef = floorf(lp);
        int ep = (int)ef;
        float mp = fexp2(lp - ef);
        // neighbors via DPP (VALU pipe); lane-0 fill bits are killed via EMIN
        float m1 = dpp_sr1_f32(bm_);
        int   e1 = dpp_sr1_i32(be);
        float m2 = dpp_sr1_f32(m1);
        int   e2 = dpp_sr1_i32(e1);
        e1 = (s >= 1) ? e1 : EMIN;
        e2 = (skip)   ? e2 : EMIN;       // skip=false kills the s-2 term
        int emax = max(be, max(e1, e2));
        int u = 127 - emax;
        int t0 = max(be + u, 0), t1 = max(e1 + u, 0), t2 = max(e2 + u, 0);
        float s0 = __int_as_float(t0 << 23);
        float s1 = __int_as_float(t1 << 23);
        float s2 = __int_as_float(t2 << 23);
        float f = bm_ * s0 + m1 * s1 + m2 * s2;   // aligned sum, f < 6
        f *= mp;
        int fi = __float_as_int(f);
        bm_ = __int_as_float((fi & 0x7FFFFF) | 0x3F800000);
        be  = emax + ep - 127 + (fi >> 23);
    };

    // group 0: t = 1..3 (Tin >= 481, always full)
    stepM(cur.y); stepM(cur.z); stepM(cur.w);
    int remaining = Tin - 4;   // steps left (total steps = Tin-1)
    int g = 1;
    while (remaining >= 4) {
        cur = nxt; nxt = nx2;
        int gi = g + 2; if (gi > 127) gi = 127;
        nx2 = g0[gi];
        stepM(cur.x); stepM(cur.y); stepM(cur.z); stepM(cur.w);
        remaining -= 4; ++g;
    }
    cur = nxt;                 // tail 0..3 steps
    if (remaining > 0) stepM(cur.x);
    if (remaining > 1) stepM(cur.y);
    if (remaining > 2) stepM(cur.z);

    int Ln = 2 * lab_lens[n] + 1;
    float ma = __shfl(bm_, Ln - 1), mb = __shfl(bm_, Ln - 2);
    int   ea = __shfl(be,  Ln - 1), eb = __shfl(be,  Ln - 2);
    int em = max(ea, eb);
    float fa = ma * __int_as_float(max(ea - em + 127, 0) << 23);
    float fb = mb * __int_as_float(max(eb - em + 127, 0) << 23);
    float v = -(flog2(fa + fb) + (float)em) * LN2;
    if (s == 0) nll[n] = v;
}

__global__ void reduce_kernel(const float* __restrict__ nll, float* __restrict__ out) {
    int s = threadIdx.x;
    float v = (s < NN) ? nll[s] : 0.f;
    #pragma unroll
    for (int off = 32; off; off >>= 1) v += __shfl_xor(v, off);
    if (s == 0) out[0] = v;
}

extern "C" void kernel_launch(void* const* d_in, const int* in_sizes, int n_in,
                              void* d_out, int out_size, void* d_ws, size_t ws_size,
                              hipStream_t stream) {
    const float* feats        = (const float*)d_in[0];
    const float* W            = (const float*)d_in[1];
    const int*   labeling     = (const int*)d_in[2];
    const int*   logit_lgts   = (const int*)d_in[3];
    const int*   labeling_lgts= (const int*)d_in[4];
    float* out = (float*)d_out;
    char* ws = (char*)d_ws;

    size_t off = 0;
    f16*   wt     = (f16*)(ws + off);   off += (size_t)CP * DD * 2;        // 1.44 MB
    f16*   fn     = (f16*)(ws + off);   off += (size_t)TT * NN * DD * 2;   // 16.8 MB
    float* ssq    = (float*)(ws + off); off += 1312 * 4;
    float* sumexp = (float*)(ws + off); off += (size_t)TT * NN * 4;        // 64 KB
    float* lp_lab = (float*)(ws + off); off += (size_t)NN * 31 * TT * 4;   // 2.0 MB
    float* nllb   = (float*)(ws + off); off += 64 * 4;

    hipMemsetAsync(ssq, 0, 1312 * 4, stream);
    hipMemsetAsync(sumexp, 0, (size_t)TT * NN * 4, stream);

    colnorm_kernel<<<dim3((CC + 63) / 64, 8), 64, 0, stream>>>(W, ssq);
    wt_kernel<<<(CP * DD) / 256, 256, 0, stream>>>(W, ssq, wt);
    fnorm_kernel<<<(TT * NN) / 4, 256, 0, stream>>>(feats, fn);
    gemm_sumexp_kernel<<<dim3(CP / 128, TT * NN / 128), 256, 0, stream>>>(fn, wt, sumexp);
    gather_kernel<<<dim3(NN, TT / 64), 256, 0, stream>>>(fn, wt, sumexp, labeling, lp_lab);
    ctc_kernel<<<NN, 64, 0, stream>>>(lp_lab, labeling, logit_lgts, labeling_lgts, nllb);
    reduce_kernel<<<1, 64, 0, stream>>>(nllb, out);

    (void)in_sizes; (void)n_in; (void)out_size; (void)ws_size;
}

// Round 13
// 167.385 us; speedup vs baseline: 1.3672x; 1.3672x over previous
//
#include <hip/hip_runtime.h>
#include <stdint.h>
#include <stddef.h>

// RadialCTC: cosine logits (norm_scale=32) -> log_softmax -> CTC(sum).
// R4: gather on MFMA. R5: shfl=ds_bpermute ~120cyc; fp8 non-scaled = f16 rate.
// R6: DPP wave_shr neighbor access. R7: log-pair-fusion regressed.
// R8: linear f32 FAILED (spread). R9: linear f64 + exact pow2 renorm: 30us.
// R10: fusion + scatter-atomics regressed. R11: LDS swizzle neutral (conflict
//      cycles hidden by wave overlap). R12: LDS-free gemm FAILED (38->95us,
//      FETCH 18->83MB: LDS staging is a bandwidth amplifier - direct VGPR
//      fragment loads delegated all reuse to L1/L2 which thrashed); mantissa/
//      exponent ctc ~37us (15-op align tree worse than 3 f64 ops). Reverted.
// R13: (a) lse subtraction is WAVE-UNIFORM in the linear ctc domain -> gather
//      writes RAW scaled logits (no sumexp dependency); ctc subtracts
//      sum_{t<Tin} log2(sumexp) once in its epilogue. This lets gather fuse
//      into the gemm launch as tail blocks (grid 1408+256, union LDS 36KB):
//      gather's ~11us runs in gemm's tail. (b) gemm epilogue column-sums on
//      VALU DPP row_ror (R10's good half) with the original contiguous
//      atomic layout (R10's regression was the scatter atomics, not the DPP).

typedef _Float16 f16;
typedef _Float16 f16x8 __attribute__((ext_vector_type(8)));
typedef float f32x4 __attribute__((ext_vector_type(4)));
typedef __attribute__((address_space(1))) void* as1_void_ptr;
typedef __attribute__((address_space(3))) void* as3_void_ptr;

#define TT 512
#define NN 32
#define CC 1296
#define DD 512
#define SS 30
#define CP 1408   // C padded to 11*128 for GEMM tiling (pad rows are zero)
#define LL 61     // 2*S+1 CTC states
#define NEGINF (-1e9f)
#define NORM_SCALE 32.0f
#define LOG2E 1.4426950408889634f
#define LN2   0.6931471805599453f
#define GEMM_BLOCKS (11 * 128)   // 1408
#define GATH_BLOCKS (NN * (TT / 64))  // 256

__device__ __forceinline__ float fexp2(float x) { return __builtin_amdgcn_exp2f(x); }
__device__ __forceinline__ float flog2(float x) { return __builtin_amdgcn_logf(x); }

// whole-wave shift-right-by-1 of a double (two 32-bit DPPs, ctrl 0x138 =
// WAVE_SHR1). Lane 0 receives +0.0.
__device__ __forceinline__ double dpp_sr1_zero64(double x) {
    long long b = __double_as_longlong(x);
    int lo = (int)(b & 0xFFFFFFFFLL);
    int hi = (int)(b >> 32);
    int lo2 = __builtin_amdgcn_update_dpp(0, lo, 0x138, 0xF, 0xF, false);
    int hi2 = __builtin_amdgcn_update_dpp(0, hi, 0x138, 0xF, 0xF, false);
    return __longlong_as_double(((long long)hi2 << 32) |
                                (unsigned long long)(unsigned int)lo2);
}
// one level of DPP row-shr int max (identity 0; operands are >=0 hi-words)
template <int CTRL>
__device__ __forceinline__ int dpp_imax_level(int m) {
    int t = __builtin_amdgcn_update_dpp(0, m, CTRL, 0xF, 0xF, false);
    return m > t ? m : t;
}
// one level of DPP row-rotate f32 add (16-lane row sum via ror 8,4,2,1)
template <int CTRL>
__device__ __forceinline__ float dpp_add_level(float m) {
    float t = __int_as_float(__builtin_amdgcn_update_dpp(
        0, __float_as_int(m), CTRL, 0xF, 0xF, false));
    return m + t;
}

// ---- col sum-of-squares of W (D x C), partial over d-chunks, atomic ----
__global__ void colnorm_kernel(const float* __restrict__ W, float* __restrict__ ssq) {
    int c = blockIdx.x * 64 + threadIdx.x;
    if (c >= CC) return;
    int d0 = blockIdx.y * 64;
    float ss = 0.f;
    #pragma unroll 8
    for (int d = d0; d < d0 + 64; ++d) {
        float v = W[(size_t)d * CC + c];
        ss += v * v;
    }
    atomicAdd(&ssq[c], ss);
}

// ---- build padded transposed normalized weight w_t (CP x DD), f16 ----
__global__ void wt_kernel(const float* __restrict__ W, const float* __restrict__ ssq,
                          f16* __restrict__ wt) {
    int idx = blockIdx.x * 256 + threadIdx.x;   // idx < CP*DD
    int c = idx >> 9, d = idx & 511;
    float v = 0.f;
    if (c < CC) v = W[(size_t)d * CC + c] * rsqrtf(ssq[c]);
    wt[idx] = (f16)v;
}

// ---- feats row-normalize -> f16 (one wave per row) ----
__global__ __launch_bounds__(256) void fnorm_kernel(const float* __restrict__ feats,
                                                    f16* __restrict__ fn) {
    int wv = (blockIdx.x * 256 + threadIdx.x) >> 6;  // row id, 0..16383
    int lane = threadIdx.x & 63;
    const float4* src = (const float4*)(feats + (size_t)wv * DD) + lane * 2;
    float4 a = src[0], b = src[1];
    float ss = a.x*a.x + a.y*a.y + a.z*a.z + a.w*a.w
             + b.x*b.x + b.y*b.y + b.z*b.z + b.w*b.w;
    #pragma unroll
    for (int off = 32; off; off >>= 1) ss += __shfl_xor(ss, off);
    float r = rsqrtf(ss);
    f16x8 o;
    o[0]=(f16)(a.x*r); o[1]=(f16)(a.y*r); o[2]=(f16)(a.z*r); o[3]=(f16)(a.w*r);
    o[4]=(f16)(b.x*r); o[5]=(f16)(b.y*r); o[6]=(f16)(b.z*r); o[7]=(f16)(b.w*r);
    *(f16x8*)(fn + (size_t)wv * DD + lane * 8) = o;
}

// ---- FUSED kernel: blocks [0,1408) = gemm_sumexp; [1408,1664) = gather.
//      LDS union: gemm uses 16KB (As 8K + Bs 8K); gather uses 36KB
//      (Bg 32K staged once + Ag 4K per-kb). ----
__global__ __launch_bounds__(256) void gg_kernel(const f16* __restrict__ A,
                                                 const f16* __restrict__ B,
                                                 float* __restrict__ sumexp,
                                                 const int* __restrict__ labels,
                                                 float* __restrict__ lp_lab) {
    __shared__ __align__(16) f16 smem[18432];    // 36 KB union
    int blk = blockIdx.x;
    int tid = threadIdx.x;
    int w = tid >> 6, lane = tid & 63;
    int lm = lane & 15, hi = lane >> 4;
    int sw = (lm >> 1) & 3;                      // channel-slot read swizzle

    if (blk < GEMM_BLOCKS) {
        // ================= GEMM + sum-exp =================
        int bm = blk / 11, bn = blk % 11;        // same-bm blocks adjacent
        f16* As = smem;                          // 128*32
        f16* Bs = smem + 4096;                   // 128*32
        int wm = w >> 1, wn = w & 1;             // 2x2 wave grid
        f32x4 acc[4][4];
        f32x4 zero = {0.f, 0.f, 0.f, 0.f};
        #pragma unroll
        for (int i = 0; i < 4; ++i)
            #pragma unroll
            for (int j = 0; j < 4; ++j) acc[i][j] = zero;

        for (int kb = 0; kb < 16; ++kb) {        // K=512, BK=32
            #pragma unroll
            for (int p = 0; p < 2; ++p) {
                int s = p * 256 + tid;           // 512 segs of 16B per tile
                int row = s >> 2;
                int ch = (s & 3) ^ ((row >> 1) & 3);
                const f16* ga = A + (size_t)(bm * 128 + row) * DD + kb * 32 + ch * 8;
                const f16* gb = B + (size_t)(bn * 128 + row) * DD + kb * 32 + ch * 8;
                __builtin_amdgcn_global_load_lds((as1_void_ptr)ga,
                    (as3_void_ptr)&As[(p * 256 + w * 64) * 8], 16, 0, 0);
                __builtin_amdgcn_global_load_lds((as1_void_ptr)gb,
                    (as3_void_ptr)&Bs[(p * 256 + w * 64) * 8], 16, 0, 0);
            }
            __syncthreads();
            f16x8 af[4], bf[4];
            #pragma unroll
            for (int i = 0; i < 4; ++i)
                af[i] = *(const f16x8*)&As[(wm * 64 + i * 16 + lm) * 32 + (hi ^ sw) * 8];
            #pragma unroll
            for (int j = 0; j < 4; ++j)
                bf[j] = *(const f16x8*)&Bs[(wn * 64 + j * 16 + lm) * 32 + (hi ^ sw) * 8];
            #pragma unroll
            for (int i = 0; i < 4; ++i)
                #pragma unroll
                for (int j = 0; j < 4; ++j)
                    acc[i][j] = __builtin_amdgcn_mfma_f32_16x16x32_f16(af[i], bf[j], acc[i][j], 0, 0, 0);
            __syncthreads();
        }
        // epilogue: 16-lane column sums on VALU DPP (row_ror 8/4/2/1)
        #pragma unroll
        for (int i = 0; i < 4; ++i) {
            float rs[4] = {0.f, 0.f, 0.f, 0.f};
            #pragma unroll
            for (int j = 0; j < 4; ++j) {
                int c = bn * 128 + wn * 64 + j * 16 + lm;   // C/D: col = lane&15
                bool ok = (c < CC);
                #pragma unroll
                for (int r = 0; r < 4; ++r)
                    rs[r] += ok ? fexp2(acc[i][j][r] * (NORM_SCALE * LOG2E)) : 0.f;
            }
            #pragma unroll
            for (int r = 0; r < 4; ++r) {
                float m = rs[r];
                m = dpp_add_level<0x128>(m);   // row_ror:8
                m = dpp_add_level<0x124>(m);   // row_ror:4
                m = dpp_add_level<0x122>(m);   // row_ror:2
                m = dpp_add_level<0x121>(m);   // row_ror:1
                rs[r] = m;
            }
            if (lm == 0) {
                int rowb = bm * 128 + wm * 64 + i * 16 + hi * 4;  // row=quad*4+reg
                #pragma unroll
                for (int r = 0; r < 4; ++r) atomicAdd(&sumexp[rowb + r], rs[r]);
            }
        }
    } else {
        // ================= gather (raw scaled logits, no lse) =================
        int idx = blk - GEMM_BLOCKS;
        int n = idx & 31, t0 = (idx >> 5) * 64;
        f16* Bg = smem;                          // 16*32*32 = 32 KB
        f16* Ag = smem + 16384;                  // 64*32 = 4 KB
        #pragma unroll
        for (int it = 0; it < 8; ++it) {         // stage all B: 2048 segs
            int s = it * 256 + tid;              // kb=s>>7, row=(s>>2)&31
            int row = (s >> 2) & 31;
            int ch = (s & 3) ^ ((row >> 1) & 3);
            int cls = (row == 0 || row > SS) ? 0 : labels[n * SS + row - 1];
            const f16* gb = B + (size_t)cls * DD + (s >> 7) * 32 + ch * 8;
            __builtin_amdgcn_global_load_lds((as1_void_ptr)gb,
                (as3_void_ptr)&Bg[(it * 256 + w * 64) * 8], 16, 0, 0);
        }
        f32x4 acc[2];
        acc[0] = (f32x4){0.f, 0.f, 0.f, 0.f};
        acc[1] = (f32x4){0.f, 0.f, 0.f, 0.f};
        for (int kb = 0; kb < 16; ++kb) {        // per-kb A staging (4 KB)
            int row = tid >> 2;
            int ch = (tid & 3) ^ ((row >> 1) & 3);
            const f16* ga = A + (size_t)((t0 + row) * NN + n) * DD + kb * 32 + ch * 8;
            __builtin_amdgcn_global_load_lds((as1_void_ptr)ga,
                (as3_void_ptr)&Ag[(w * 64) * 8], 16, 0, 0);
            __syncthreads();                     // covers Bg on kb==0
            f16x8 af  = *(const f16x8*)&Ag[(w * 16 + lm) * 32 + (hi ^ sw) * 8];
            f16x8 bf0 = *(const f16x8*)&Bg[kb * 1024 + lm * 32 + (hi ^ sw) * 8];
            f16x8 bf1 = *(const f16x8*)&Bg[kb * 1024 + (16 + lm) * 32 + (hi ^ sw) * 8];
            acc[0] = __builtin_amdgcn_mfma_f32_16x16x32_f16(af, bf0, acc[0], 0, 0, 0);
            acc[1] = __builtin_amdgcn_mfma_f32_16x16x32_f16(af, bf1, acc[1], 0, 0, 0);
            __syncthreads();
        }
        #pragma unroll
        for (int jn = 0; jn < 2; ++jn) {
            int j = jn * 16 + lm;
            if (j >= 31) continue;
            float* dst = lp_lab + ((size_t)n * 31 + j) * TT + t0;
            #pragma unroll
            for (int r = 0; r < 4; ++r) {
                int tl = w * 16 + hi * 4 + r;
                dst[tl] = acc[jn][r] * (NORM_SCALE * LOG2E);   // RAW log2-logit
            }
        }
    }
}

// ---- CTC alpha recursion, LINEAR f64, raw logits: one wave/sample.
//      Per-step -lse is wave-uniform -> folded out; epilogue subtracts
//      sum_{t<Tin} log2(sumexp[t,n]). Exact pow2 renorm every 4 steps. ----
__global__ void ctc_kernel(const float* __restrict__ lp_lab,
                           const float* __restrict__ sumexp,
                           const int* __restrict__ labels,
                           const int* __restrict__ in_lens, const int* __restrict__ lab_lens,
                           float* __restrict__ nll) {
    int n = blockIdx.x;
    int s = threadIdx.x;     // 64 lanes; states 0..60 valid
    bool valid = s < LL;
    int ext = (valid && (s & 1)) ? labels[n * SS + (s >> 1)] : 0;
    int jmap = (valid && (s & 1)) ? ((s >> 1) + 1) : 0;   // state -> class slot
    int ext2 = __shfl_up(ext, 2);
    double skipd = ((s >= 2) && valid && (ext != ext2)) ? 1.0 : 0.0;
    int Tin = in_lens[n];    // wave-uniform; freeze == stop at t = Tin-1
    const float4* g0 = (const float4*)(lp_lab + ((size_t)n * 31 + jmap) * TT);

    float4 cur = g0[0];
    float4 nxt = g0[1];
    float4 nx2 = g0[2];
    double beta = (s <= 1) ? (double)fexp2(cur.x) : 0.0;
    int Mi = 0;              // running log2 scale

    auto stepL = [&](float lp) {
        double P = (double)fexp2(lp);      // lp in [-47,47]: f32-safe
        double b1 = dpp_sr1_zero64(beta);
        double b2 = dpp_sr1_zero64(b1);
        beta = (beta + b1 + b2 * skipd) * P;
    };
    auto renorm = [&]() {
        int h = (int)(__double_as_longlong(beta) >> 32);  // beta>=0: monotone
        h = dpp_imax_level<0x111>(h);
        h = dpp_imax_level<0x112>(h);
        h = dpp_imax_level<0x114>(h);
        h = dpp_imax_level<0x118>(h);        // row maxes in lanes 15/31/47/63
        int r0 = __builtin_amdgcn_readlane(h, 15);
        int r1 = __builtin_amdgcn_readlane(h, 31);
        int r2 = __builtin_amdgcn_readlane(h, 47);
        int r3 = __builtin_amdgcn_readlane(h, 63);
        int mx = max(max(r0, r1), max(r2, r3));
        int e11 = mx >> 20;                  // biased 11-bit exponent
        double scale = __longlong_as_double((long long)(2046 - e11) << 52);
        beta *= scale;                       // exact power-of-2
        Mi += e11 - 1023;
    };

    // group 0: t = 1..3 (Tin >= 481, always full)
    stepL(cur.y); stepL(cur.z); stepL(cur.w);
    renorm();
    int remaining = Tin - 4;   // steps left (total steps = Tin-1)
    int g = 1;
    while (remaining >= 4) {
        cur = nxt; nxt = nx2;
        int gi = g + 2; if (gi > 127) gi = 127;
        nx2 = g0[gi];
        stepL(cur.x); stepL(cur.y); stepL(cur.z); stepL(cur.w);
        renorm();
        remaining -= 4; ++g;
    }
    cur = nxt;                 // tail 0..3 steps
    if (remaining > 0) stepL(cur.x);
    if (remaining > 1) stepL(cur.y);
    if (remaining > 2) stepL(cur.z);

    // ---- epilogue: S = sum_{t<Tin} log2(sumexp[t*32+n]) (all 64 lanes) ----
    float S = 0.f;
    #pragma unroll
    for (int k = 0; k < 8; ++k) {
        int t = (k << 6) + s;
        if (t < Tin) S += flog2(sumexp[t * NN + n]);
    }
    #pragma unroll
    for (int off = 32; off; off >>= 1) S += __shfl_xor(S, off);

    int Ln = 2 * lab_lens[n] + 1;
    double last  = __shfl(beta, Ln - 1);
    double last2 = __shfl(beta, Ln - 2);
    double sm = last + last2;
    long long bb = __double_as_longlong(sm);
    int e = (int)(bb >> 52) - 1023;
    double mant = __longlong_as_double((bb & 0xFFFFFFFFFFFFFLL) | (1023LL << 52));
    float v = -(flog2((float)mant) + (float)(e + Mi) - S) * LN2;
    if (s == 0) nll[n] = v;
}

__global__ void reduce_kernel(const float* __restrict__ nll, float* __restrict__ out) {
    int s = threadIdx.x;
    float v = (s < NN) ? nll[s] : 0.f;
    #pragma unroll
    for (int off = 32; off; off >>= 1) v += __shfl_xor(v, off);
    if (s == 0) out[0] = v;
}

extern "C" void kernel_launch(void* const* d_in, const int* in_sizes, int n_in,
                              void* d_out, int out_size, void* d_ws, size_t ws_size,
                              hipStream_t stream) {
    const float* feats        = (const float*)d_in[0];
    const float* W            = (const float*)d_in[1];
    const int*   labeling     = (const int*)d_in[2];
    const int*   logit_lgts   = (const int*)d_in[3];
    const int*   labeling_lgts= (const int*)d_in[4];
    float* out = (float*)d_out;
    char* ws = (char*)d_ws;

    size_t off = 0;
    f16*   wt     = (f16*)(ws + off);   off += (size_t)CP * DD * 2;        // 1.44 MB
    f16*   fn     = (f16*)(ws + off);   off += (size_t)TT * NN * DD * 2;   // 16.8 MB
    float* ssq    = (float*)(ws + off); off += 1312 * 4;
    float* sumexp = (float*)(ws + off); off += (size_t)TT * NN * 4;        // 64 KB, [t][n]
    float* lp_lab = (float*)(ws + off); off += (size_t)NN * 31 * TT * 4;   // 2.0 MB
    float* nllb   = (float*)(ws + off); off += 64 * 4;

    hipMemsetAsync(ssq, 0, 1312 * 4, stream);
    hipMemsetAsync(sumexp, 0, (size_t)TT * NN * 4, stream);

    colnorm_kernel<<<dim3((CC + 63) / 64, 8), 64, 0, stream>>>(W, ssq);
    wt_kernel<<<(CP * DD) / 256, 256, 0, stream>>>(W, ssq, wt);
    fnorm_kernel<<<(TT * NN) / 4, 256, 0, stream>>>(feats, fn);
    gg_kernel<<<GEMM_BLOCKS + GATH_BLOCKS, 256, 0, stream>>>(fn, wt, sumexp, labeling, lp_lab);
    ctc_kernel<<<NN, 64, 0, stream>>>(lp_lab, sumexp, labeling, logit_lgts, labeling_lgts, nllb);
    reduce_kernel<<<1, 64, 0, stream>>>(nllb, out);

    (void)in_sizes; (void)n_in; (void)out_size; (void)ws_size;
}